// Round 8
// baseline (459.944 us; speedup 1.0000x reference)
//
#include <hip/hip_runtime.h>
#include <cstdint>
#include <cstddef>

typedef _Float16 half8 __attribute__((ext_vector_type(8)));
typedef _Float16 half4 __attribute__((ext_vector_type(4)));
typedef float f32x4 __attribute__((ext_vector_type(4)));
typedef int iv4 __attribute__((ext_vector_type(4)));

#define GAT_N 8192
#define GAT_F 256
#define GAT_NQ 8     // key slices of 1024
#define GAT_ALPHA 0.2f
#define GAT_LOG2E 1.4426950408889634f

// Monotone float->uint encoding for atomicMax over floats of any sign.
__device__ inline unsigned enc_f32(float x) {
    unsigned b = __float_as_uint(x);
    return (b & 0x80000000u) ? ~b : (b | 0x80000000u);
}
__device__ inline float dec_f32(unsigned u) {
    unsigned b = (u & 0x80000000u) ? (u ^ 0x80000000u) : ~u;
    return __uint_as_float(b);
}

// Compare+pack 8 adj int32s (two iv4) into an 8-bit edge mask.
__device__ inline unsigned pack8(iv4 v0, iv4 v1) {
    return (unsigned)(v0[0] > 0)        | ((unsigned)(v0[1] > 0) << 1)
         | ((unsigned)(v0[2] > 0) << 2) | ((unsigned)(v0[3] > 0) << 3)
         | ((unsigned)(v1[0] > 0) << 4) | ((unsigned)(v1[1] > 0) << 5)
         | ((unsigned)(v1[2] > 0) << 6) | ((unsigned)(v1[3] > 0) << 7);
}

// whT2 layout: 128 tiles (64 keys each) x [oct(8)][feat(256)][key&7(8)] fp16.
// addr(halves) = (key>>6)*16384 + ((key&63)>>3)*2048 + feat*8 + (key&7).
// A 32-key window w (0..255) is the CONTIGUOUS 16 KB chunk at halves w*8192.

// ---------------------------------------------------------------------------
// K0b: W -> fp16 transposed WT[n][k]; init encoded f2max.
// ---------------------------------------------------------------------------
__global__ __launch_bounds__(256) void gat_k0b_convert(
    const float* __restrict__ W, _Float16* __restrict__ WT,
    unsigned* __restrict__ f2mxEnc)
{
    const int g = blockIdx.x * 256 + threadIdx.x;
    if (g == 0) *f2mxEnc = 0u;                          // enc(-FLT_MAX)
    const int k = g >> 8, n = g & 255;
    WT[n * GAT_F + k] = (_Float16)W[g];
}

// ---------------------------------------------------------------------------
// K1: Wh = h @ W via fp16 MFMA. grid 512 x 256 thr: block = 16 rows (=16
// keys), wave wv = col-quarter (64 cols, 4 tiles). Cross-wave f1/f2 via LDS.
// Epilogue writes whT2 in TILED layout (key of K3 = row of Wh).
// ---------------------------------------------------------------------------
__global__ __launch_bounds__(256, 2) void gat_k1_gemm(
    const float* __restrict__ h, const _Float16* __restrict__ WT,
    const float* __restrict__ a, _Float16* __restrict__ whT2,
    float* __restrict__ f1L, float* __restrict__ f2L,
    unsigned* __restrict__ f2mxEnc)
{
    __shared__ float sP1[4][16], sP2[4][16];
    const int wv = threadIdx.x >> 6;
    const int lane = threadIdx.x & 63;
    const int l15 = lane & 15;
    const int quad = lane >> 4;
    const int r0 = blockIdx.x * 16;

    f32x4 acc[4];
    #pragma unroll
    for (int t = 0; t < 4; ++t) { f32x4 z = {0.f,0.f,0.f,0.f}; acc[t] = z; }

    #pragma unroll
    for (int k0 = 0; k0 < GAT_F; k0 += 32) {
        const float* ap = h + (size_t)(r0 + l15) * GAT_F + k0 + quad * 8;
        const float4 a0 = *reinterpret_cast<const float4*>(ap);
        const float4 a1 = *reinterpret_cast<const float4*>(ap + 4);
        half8 af;
        af[0] = (_Float16)a0.x; af[1] = (_Float16)a0.y;
        af[2] = (_Float16)a0.z; af[3] = (_Float16)a0.w;
        af[4] = (_Float16)a1.x; af[5] = (_Float16)a1.y;
        af[6] = (_Float16)a1.z; af[7] = (_Float16)a1.w;
        #pragma unroll
        for (int t = 0; t < 4; ++t) {
            half8 bf = *reinterpret_cast<const half8*>(
                WT + (size_t)(wv * 64 + t * 16 + l15) * GAT_F + k0 + quad * 8);
            acc[t] = __builtin_amdgcn_mfma_f32_16x16x32_f16(af, bf, acc[t], 0, 0, 0);
        }
    }

    float p1[4] = {0.f,0.f,0.f,0.f}, p2[4] = {0.f,0.f,0.f,0.f};
    #pragma unroll
    for (int t = 0; t < 4; ++t) {
        float a1c = a[wv * 64 + t * 16 + l15];
        float a2c = a[GAT_F + wv * 64 + t * 16 + l15];
        #pragma unroll
        for (int r = 0; r < 4; ++r) {
            p1[r] = fmaf(acc[t][r], a1c, p1[r]);
            p2[r] = fmaf(acc[t][r], a2c, p2[r]);
        }
    }
    #pragma unroll
    for (int off = 1; off < 16; off <<= 1) {
        #pragma unroll
        for (int r = 0; r < 4; ++r) {
            p1[r] += __shfl_xor(p1[r], off);
            p2[r] += __shfl_xor(p2[r], off);
        }
    }
    if (l15 == 0) {
        #pragma unroll
        for (int r = 0; r < 4; ++r) {
            sP1[wv][quad * 4 + r] = p1[r];
            sP2[wv][quad * 4 + r] = p2[r];
        }
    }
    __syncthreads();
    if (threadIdx.x < 16) {
        const int row = threadIdx.x;
        const float s1 = (sP1[0][row] + sP1[1][row] + sP1[2][row] + sP1[3][row]) * GAT_LOG2E;
        const float s2 = (sP2[0][row] + sP2[1][row] + sP2[2][row] + sP2[3][row]) * GAT_LOG2E;
        f1L[r0 + row] = s1;
        f2L[r0 + row] = s2;
        float mx = s2;
        #pragma unroll
        for (int off = 1; off < 16; off <<= 1) mx = fmaxf(mx, __shfl_xor(mx, off));
        if (row == 0) atomicMax(f2mxEnc, enc_f32(mx));
    }

    // Tiled whT2 store. Keys r0+quad*4+r, feat c:
    // tile = r0>>6, oct = ((r0&63)>>3)+(quad>>1), key&7 = (quad&1)*4+r.
    const size_t tbase = (size_t)(r0 >> 6) * 16384
                       + (((r0 & 63) >> 3) + (quad >> 1)) * 2048
                       + (quad & 1) * 4;
    #pragma unroll
    for (int t = 0; t < 4; ++t) {
        const int c = wv * 64 + t * 16 + l15;
        half4 hv;
        #pragma unroll
        for (int r = 0; r < 4; ++r) hv[r] = (_Float16)acc[t][r];
        *reinterpret_cast<half4*>(whT2 + tbase + c * 8) = hv;
    }
}

// ---------------------------------------------------------------------------
// K3: fused masked softmax-numerator x V. R18: DEPTH-2 ADJ PREFETCH VIA LDS
// + COUNTED VMCNT. Diagnosis (R1/R2 delta + R5 PMC + R4/R7 neutrality):
// adj rate = issue-per-step / step-time, capped at 1 step of lookahead by
// the __syncthreads vmcnt(0) drain; reg-held depth-2 spilled (R5/R6).
// Fix: adj(s+2) prefetched by global_load_lds into a wave-private 2-slot
// LDS board (ZERO register cost). Step: [STAGE(s+1) | ADJGL(s+2)] ->
// compute -> vmcnt(6) (retires adjgl(s+1), a full step old) -> ds_read+pack
// masks(s+1) -> vmcnt(2) (retires stage(s+1); adjgl(s+2) stays in flight)
// -> s_barrier. Nothing drains to 0 in the main loop. sAdj layout is
// cell-grouped [g(8)][row(16)] 16B cells so the mask ds_read is the same
// unit-stride-16B pattern as the (conflict-free, PMC=0) B reads.
// Compute/mask bit order identical to R7 -> bit-identical output.
// grid = 128 rb x 8 q = 1024 blocks; LDS 52 KB -> 3 blocks/CU; ~125 regs.
// ---------------------------------------------------------------------------
__global__ __launch_bounds__(256, 3) void gat_k3_attn(
    const int* __restrict__ adj, const float* __restrict__ f1L,
    const float* __restrict__ f2L, const unsigned* __restrict__ f2mxEnc,
    const _Float16* __restrict__ whT2,
    _Float16* __restrict__ Ph,     // 8 slabs x [512 wid][4096] fp16, permuted
    float* __restrict__ L)         // [8][8192]
{
    __shared__ __align__(16) _Float16 sB[2][8192];   // 2 x 16 KB (32-key tile)
    __shared__ __align__(16) float sF2[1024];        // 4 KB f2 slice
    __shared__ __align__(16) int sAdj[2][4][512];    // 16 KB: slot x wave x 2KB

    const int bx = blockIdx.x;
    const int q  = bx & 7;           // key slice 0..7
    const int rb = bx >> 3;          // row group 0..127
    const int wv = threadIdx.x >> 6;
    const int lane = threadIdx.x & 63;
    const int l15 = lane & 15;
    const int quad = lane >> 4;

    const int kq = q * 1024;
    const int r0 = rb * 64 + wv * 16;
    const int rA = r0 + l15;

    const float fmxL = dec_f32(*f2mxEnc);
    const float f1A = f1L[rA];
    const float sAv = f1A + fmxL;
    const float CA = fmaxf(sAv, GAT_ALPHA * sAv);
    // exp2 arg = max(xa, a*xa) - C = max((f1-C)+f2j, (a*f1-C)+a*f2j)
    const float uA = f1A - CA, vA = GAT_ALPHA * f1A - CA;

    // f2 slice -> LDS (one float4 per thread; visible after prologue barrier).
    {
        const float4 v = *reinterpret_cast<const float4*>(f2L + kq + threadIdx.x * 4);
        *reinterpret_cast<float4*>(&sF2[threadIdx.x * 4]) = v;
    }

    f32x4 acc[16];
    #pragma unroll
    for (int t = 0; t < 16; ++t) { f32x4 z = {0.f,0.f,0.f,0.f}; acc[t] = z; }
    float d0 = 0.f;

    // ADJGL(slot, s): prefetch this wave's 16-row x 32-key adj window for
    // step s into sAdj[slot][wv] via global_load_lds (no VGPR held).
    // Cell-grouped layout: cell (g=int4-group 0..7, row 0..15) at int index
    // g*64 + row*4. Instr k covers cells k*64+l: g = k*4+(l>>4), row = l&15.
    // Global source per lane: adj[(r0+row)*N + kq + s*32 + g*4] (16 B).
    const int* adjB0 = adj + (size_t)r0 * GAT_N + kq;
    #define ADJGL(slot, s)                                                     \
        {                                                                      \
            _Pragma("unroll")                                                  \
            for (int k = 0; k < 2; ++k) {                                      \
                const int* gp = adjB0 + (size_t)(lane & 15) * GAT_N            \
                              + (s) * 32 + (k * 4 + (lane >> 4)) * 4;          \
                int* lp = &sAdj[slot][wv][k * 256];                            \
                __builtin_amdgcn_global_load_lds(                              \
                    (const __attribute__((address_space(1))) void*)gp,         \
                    (__attribute__((address_space(3))) void*)lp, 16, 0, 0);    \
            }                                                                  \
        }
    // Mask read: lane (l15, quad) reads cells (quad*2, l15) and (quad*2+1,
    // l15) -> ints [quad*8, +8) of row l15 = same bits as R7's direct load.
    #define ADJREAD_PACK(slot, m)                                              \
        {                                                                      \
            iv4 a0 = *reinterpret_cast<const iv4*>(                            \
                &sAdj[slot][wv][(quad * 2) * 64 + l15 * 4]);                   \
            iv4 a1 = *reinterpret_cast<const iv4*>(                            \
                &sAdj[slot][wv][(quad * 2 + 1) * 64 + l15 * 4]);               \
            m = pack8(a0, a1);                                                 \
        }

    // STAGE(buf, step): 32-key window = contiguous 16 KB at halves
    // (q*32+step)*8192. Wave wv covers [wv*2048, +2048) halves; 4 instrs of
    // 1 KB. PER-LANE global addr = base + lane*8 halves; LDS dest uniform.
    const _Float16* tile0 = whT2 + (size_t)(q * 32) * 8192
                          + wv * 2048 + (size_t)lane * 8;
    #define STAGE(buf, step)                                                   \
        {                                                                      \
            _Pragma("unroll")                                                  \
            for (int i = 0; i < 4; ++i) {                                      \
                const _Float16* gp = tile0 + (size_t)(step) * 8192 + i * 512;  \
                _Float16* lp = &sB[buf][wv * 2048 + i * 512];                  \
                __builtin_amdgcn_global_load_lds(                              \
                    (const __attribute__((address_space(1))) void*)gp,         \
                    (__attribute__((address_space(3))) void*)lp, 16, 0, 0);    \
            }                                                                  \
        }

    // Prologue: stage(0); adjgl(1) into slot 1; adj(0) direct to regs; pack.
    // __syncthreads drains everything once (prologue only) + publishes sF2.
    unsigned cmA;
    STAGE(0, 0)
    ADJGL(1, 1)
    {
        const int* pa = adj + (size_t)rA * GAT_N + kq + quad * 8;
        iv4 x0 = *reinterpret_cast<const iv4*>(pa);
        iv4 x1 = *reinterpret_cast<const iv4*>(pa + 4);
        cmA = pack8(x0, x1);
    }
    __syncthreads();

    const _Float16* const sflat = &sB[0][0];

    for (int step = 0; step < 32; ++step) {   // 32 keys per step
        const int cur = step & 1;
        // Step-top issues. ORDER MATTERS for the counted vmcnt below:
        // stage first, adjgl last (sched_barrier pins the boundary).
        if (step < 31) STAGE(1 - cur, step + 1)
        __builtin_amdgcn_sched_barrier(0);
        if (step < 30) ADJGL(step & 1, step + 2)
        __builtin_amdgcn_sched_barrier(0);

        // ---- compute: keys step*32 .. +32 (no vmem ops inside) ----
        const float* fp = &sF2[step * 32 + quad * 8];
        const float4 cfa = *reinterpret_cast<const float4*>(fp);
        const float4 cfb = *reinterpret_cast<const float4*>(fp + 4);
        const float f2v[8] = {cfa.x, cfa.y, cfa.z, cfa.w,
                              cfb.x, cfb.y, cfb.z, cfb.w};
        float af2[8];
        #pragma unroll
        for (int j = 0; j < 8; ++j) af2[j] = GAT_ALPHA * f2v[j];

        half8 pA;
        #pragma unroll
        for (int j = 0; j < 8; ++j) {
            float pa = __builtin_amdgcn_exp2f(fmaxf(uA + f2v[j], vA + af2[j]));
            pa = (cmA & (1u << j)) ? pa : 0.f;
            d0 += pa;
            pA[j] = (_Float16)pa;
        }

        const _Float16* bk = sflat + cur * 8192 + quad * 2048 + l15 * 8;
        __builtin_amdgcn_s_setprio(1);
        #pragma unroll
        for (int t = 0; t < 16; ++t) {
            half8 bf = *reinterpret_cast<const half8*>(bk + t * 128);
            acc[t] = __builtin_amdgcn_mfma_f32_16x16x32_f16(pA, bf, acc[t], 0, 0, 0);
        }
        __builtin_amdgcn_s_setprio(0);

        if (step < 31) {
            // Retire adjgl(step+1) (issued a full step ago). Outstanding
            // newer: stage(step+1)=4 + adjgl(step+2)=2 (0 at step 30).
            if (step < 30) { asm volatile("s_waitcnt vmcnt(6)" ::: "memory"); }
            else           { asm volatile("s_waitcnt vmcnt(4)" ::: "memory"); }
            __builtin_amdgcn_sched_barrier(0);
            ADJREAD_PACK((step + 1) & 1, cmA)
            // Retire stage(step+1); leave adjgl(step+2) in flight.
            if (step < 30) { asm volatile("s_waitcnt vmcnt(2)" ::: "memory"); }
            else           { asm volatile("s_waitcnt vmcnt(0)" ::: "memory"); }
            __builtin_amdgcn_sched_barrier(0);
            __builtin_amdgcn_s_barrier();     // buf[1-cur] ready block-wide
        }
    }
    #undef STAGE
    #undef ADJGL
    #undef ADJREAD_PACK

    // Row denominators: sum the 4 quads of each row.
    d0 += __shfl_xor(d0, 16); d0 += __shfl_xor(d0, 32);
    if (lane < 16) L[q * GAT_N + rA] = d0;

    // Coalesced permuted fp16 partial store; NONTEMPORAL (write-once stream).
    const int wid = rb * 4 + wv;                       // 0..511
    _Float16* Pq = Ph + ((size_t)q * 512 + wid) * 4096;
    #pragma unroll
    for (int t = 0; t < 16; ++t) {
        half4 hv;
        #pragma unroll
        for (int r = 0; r < 4; ++r) hv[r] = (_Float16)acc[t][r];
        __builtin_nontemporal_store(hv,
            reinterpret_cast<half4*>(Pq + (size_t)((t * 64 + lane) * 4)));
    }
}

// ---------------------------------------------------------------------------
// K4: un-permute + combine 8 fp16 partials, normalize, ELU, write out.
// 16-row chunks (wid 0..511), 4 blocks per chunk.
// ---------------------------------------------------------------------------
__global__ __launch_bounds__(256) void gat_k4_final(
    const _Float16* __restrict__ Ph, const float* __restrict__ L,
    float* __restrict__ out)
{
    const int tid = threadIdx.x;
    const int wid = blockIdx.x >> 2;                   // 16-row chunk 0..511
    __shared__ float s_rl[16];
    if (tid < 16) {
        const int row = wid * 16 + tid;
        float s = 0.f;
        #pragma unroll
        for (int q = 0; q < GAT_NQ; ++q) s += L[q * GAT_N + row];
        s_rl[tid] = 1.0f / fmaxf(s, 1e-30f);
    }
    __syncthreads();

    const int idx = blockIdx.x * 256 + tid;            // half4 position
    const int rem = idx & 1023;                        // within chunk
    const int lane = rem & 63;
    const int t = rem >> 6;                            // feat tile 0..15
    const int l15 = lane & 15, quad = lane >> 4;
    const int lrow0 = quad * 4;                        // local rows lrow0..+3
    const int col = t * 16 + l15;

    float accv[4] = {0.f, 0.f, 0.f, 0.f};
    #pragma unroll
    for (int q = 0; q < GAT_NQ; ++q) {
        half4 v = *reinterpret_cast<const half4*>(
            Ph + ((size_t)q * 512 + wid) * 4096 + (size_t)rem * 4);
        #pragma unroll
        for (int r = 0; r < 4; ++r) accv[r] += (float)v[r];
    }
    #pragma unroll
    for (int r = 0; r < 4; ++r) {
        const float v = accv[r] * s_rl[lrow0 + r];
        const float o = v > 0.f ? v : expm1f(v);
        out[(size_t)(wid * 16 + lrow0 + r) * GAT_F + col] = o;
    }
}

// ---------------------------------------------------------------------------
extern "C" void kernel_launch(void* const* d_in, const int* in_sizes, int n_in,
                              void* d_out, int out_size, void* d_ws, size_t ws_size,
                              hipStream_t stream)
{
    const float* h   = (const float*)d_in[0];
    const int*   adj = (const int*)d_in[1];
    // d_in[2] = cv_values: constant per softmax row -> cancels exactly; unused.
    const float* W   = (const float*)d_in[3];
    const float* a   = (const float*)d_in[4];
    float* out = (float*)d_out;
    char* ws = (char*)d_ws;

    const size_t SLAB = (size_t)GAT_N * GAT_F * 2;     // 4 MiB (fp16 matrix)

    size_t off = 0;
    _Float16* whT2 = (_Float16*)(ws + off); off += SLAB;           // 4 MiB tiled
    _Float16* Ph  = (_Float16*)(ws + off); off += GAT_NQ * SLAB;   // 32 MiB
    _Float16* WT  = (_Float16*)(ws + off); off += (size_t)GAT_F * GAT_F * 2;  // 128 KiB
    float* f1L = (float*)(ws + off); off += GAT_N * 4;
    float* f2L = (float*)(ws + off); off += GAT_N * 4;
    float* L   = (float*)(ws + off); off += GAT_NQ * GAT_N * 4;
    unsigned* f2mxEnc = (unsigned*)(ws + off); off += 256;

    gat_k0b_convert<<<256, 256, 0, stream>>>(W, WT, f2mxEnc);
    gat_k1_gemm<<<512, 256, 0, stream>>>(h, WT, a, whT2, f1L, f2L, f2mxEnc);
    gat_k3_attn<<<1024, 256, 0, stream>>>(adj, f1L, f2L, f2mxEnc, whT2, Ph, L);
    gat_k4_final<<<2048, 256, 0, stream>>>(Ph, L, out);
}

// Round 10
// 415.259 us; speedup vs baseline: 1.1076x; 1.1076x over previous
//
#include <hip/hip_runtime.h>
#include <cstdint>
#include <cstddef>

typedef _Float16 half8 __attribute__((ext_vector_type(8)));
typedef _Float16 half4 __attribute__((ext_vector_type(4)));
typedef float f32x4 __attribute__((ext_vector_type(4)));
typedef int iv4 __attribute__((ext_vector_type(4)));

#define GAT_N 8192
#define GAT_F 256
#define GAT_NQ 8     // key slices of 1024
#define GAT_ALPHA 0.2f
#define GAT_LOG2E 1.4426950408889634f

// Monotone float->uint encoding for atomicMax over floats of any sign.
__device__ inline unsigned enc_f32(float x) {
    unsigned b = __float_as_uint(x);
    return (b & 0x80000000u) ? ~b : (b | 0x80000000u);
}
__device__ inline float dec_f32(unsigned u) {
    unsigned b = (u & 0x80000000u) ? (u ^ 0x80000000u) : ~u;
    return __uint_as_float(b);
}

// Compare+pack 8 adj int32s (two iv4) into an 8-bit edge mask.
__device__ inline unsigned pack8(iv4 v0, iv4 v1) {
    return (unsigned)(v0[0] > 0)        | ((unsigned)(v0[1] > 0) << 1)
         | ((unsigned)(v0[2] > 0) << 2) | ((unsigned)(v0[3] > 0) << 3)
         | ((unsigned)(v1[0] > 0) << 4) | ((unsigned)(v1[1] > 0) << 5)
         | ((unsigned)(v1[2] > 0) << 6) | ((unsigned)(v1[3] > 0) << 7);
}

// whT2 layout: 128 tiles (64 keys each) x [oct(8)][feat(256)][key&7(8)] fp16.
// addr(halves) = (key>>6)*16384 + ((key&63)>>3)*2048 + feat*8 + (key&7).
// This is EXACTLY the K3 LDS chunk order, so staging is a linear copy with
// unit-stride lanes (global_load_lds: per-lane global addr, implicit lane*16
// LDS dest).

// ---------------------------------------------------------------------------
// K0b: W -> fp16 transposed WT[n][k]; init encoded f2max.
// ---------------------------------------------------------------------------
__global__ __launch_bounds__(256) void gat_k0b_convert(
    const float* __restrict__ W, _Float16* __restrict__ WT,
    unsigned* __restrict__ f2mxEnc)
{
    const int g = blockIdx.x * 256 + threadIdx.x;
    if (g == 0) *f2mxEnc = 0u;                          // enc(-FLT_MAX)
    const int k = g >> 8, n = g & 255;
    WT[n * GAT_F + k] = (_Float16)W[g];
}

// ---------------------------------------------------------------------------
// K1: Wh = h @ W via fp16 MFMA. grid 512 x 256 thr: block = 16 rows (=16
// keys), wave wv = col-quarter (64 cols, 4 tiles). Cross-wave f1/f2 via LDS.
// Epilogue writes whT2 in TILED layout (key of K3 = row of Wh).
// ---------------------------------------------------------------------------
__global__ __launch_bounds__(256, 2) void gat_k1_gemm(
    const float* __restrict__ h, const _Float16* __restrict__ WT,
    const float* __restrict__ a, _Float16* __restrict__ whT2,
    float* __restrict__ f1L, float* __restrict__ f2L,
    unsigned* __restrict__ f2mxEnc)
{
    __shared__ float sP1[4][16], sP2[4][16];
    const int wv = threadIdx.x >> 6;
    const int lane = threadIdx.x & 63;
    const int l15 = lane & 15;
    const int quad = lane >> 4;
    const int r0 = blockIdx.x * 16;

    f32x4 acc[4];
    #pragma unroll
    for (int t = 0; t < 4; ++t) { f32x4 z = {0.f,0.f,0.f,0.f}; acc[t] = z; }

    #pragma unroll
    for (int k0 = 0; k0 < GAT_F; k0 += 32) {
        const float* ap = h + (size_t)(r0 + l15) * GAT_F + k0 + quad * 8;
        const float4 a0 = *reinterpret_cast<const float4*>(ap);
        const float4 a1 = *reinterpret_cast<const float4*>(ap + 4);
        half8 af;
        af[0] = (_Float16)a0.x; af[1] = (_Float16)a0.y;
        af[2] = (_Float16)a0.z; af[3] = (_Float16)a0.w;
        af[4] = (_Float16)a1.x; af[5] = (_Float16)a1.y;
        af[6] = (_Float16)a1.z; af[7] = (_Float16)a1.w;
        #pragma unroll
        for (int t = 0; t < 4; ++t) {
            half8 bf = *reinterpret_cast<const half8*>(
                WT + (size_t)(wv * 64 + t * 16 + l15) * GAT_F + k0 + quad * 8);
            acc[t] = __builtin_amdgcn_mfma_f32_16x16x32_f16(af, bf, acc[t], 0, 0, 0);
        }
    }

    float p1[4] = {0.f,0.f,0.f,0.f}, p2[4] = {0.f,0.f,0.f,0.f};
    #pragma unroll
    for (int t = 0; t < 4; ++t) {
        float a1c = a[wv * 64 + t * 16 + l15];
        float a2c = a[GAT_F + wv * 64 + t * 16 + l15];
        #pragma unroll
        for (int r = 0; r < 4; ++r) {
            p1[r] = fmaf(acc[t][r], a1c, p1[r]);
            p2[r] = fmaf(acc[t][r], a2c, p2[r]);
        }
    }
    #pragma unroll
    for (int off = 1; off < 16; off <<= 1) {
        #pragma unroll
        for (int r = 0; r < 4; ++r) {
            p1[r] += __shfl_xor(p1[r], off);
            p2[r] += __shfl_xor(p2[r], off);
        }
    }
    if (l15 == 0) {
        #pragma unroll
        for (int r = 0; r < 4; ++r) {
            sP1[wv][quad * 4 + r] = p1[r];
            sP2[wv][quad * 4 + r] = p2[r];
        }
    }
    __syncthreads();
    if (threadIdx.x < 16) {
        const int row = threadIdx.x;
        const float s1 = (sP1[0][row] + sP1[1][row] + sP1[2][row] + sP1[3][row]) * GAT_LOG2E;
        const float s2 = (sP2[0][row] + sP2[1][row] + sP2[2][row] + sP2[3][row]) * GAT_LOG2E;
        f1L[r0 + row] = s1;
        f2L[r0 + row] = s2;
        float mx = s2;
        #pragma unroll
        for (int off = 1; off < 16; off <<= 1) mx = fmaxf(mx, __shfl_xor(mx, off));
        if (row == 0) atomicMax(f2mxEnc, enc_f32(mx));
    }

    // Tiled whT2 store. Keys r0+quad*4+r, feat c:
    // tile = r0>>6, oct = ((r0&63)>>3)+(quad>>1), key&7 = (quad&1)*4+r.
    const size_t tbase = (size_t)(r0 >> 6) * 16384
                       + (((r0 & 63) >> 3) + (quad >> 1)) * 2048
                       + (quad & 1) * 4;
    #pragma unroll
    for (int t = 0; t < 4; ++t) {
        const int c = wv * 64 + t * 16 + l15;
        half4 hv;
        #pragma unroll
        for (int r = 0; r < 4; ++r) hv[r] = (_Float16)acc[t][r];
        *reinterpret_cast<half4*>(whT2 + tbase + c * 8) = hv;
    }
}

// ---------------------------------------------------------------------------
// K3: fused masked softmax-numerator x V. R19 = R2 champion (430 us) with
// ONE mechanism change: the 268 MB one-shot adj stream is loaded NONTEMPORAL
// so it stops evicting the L2-resident whT2 staging source (4 MiB, re-read
// 64x = 256 MB of stage traffic). R2's stage global_load_lds otherwise
// misses to L3/HBM (~600-900 cy vs ~200), and the per-step vmcnt(0) drain
// puts that latency on the critical path of every step. Ph partial stores
// (write-once, 32 MB) are likewise nontemporal. Everything else -- grid,
// LDS, barriers, mask bits, FP op order -- is byte-identical to R2, so the
// output is bit-identical. grid = 64 rb x 8 q = 512 blocks at (256,2).
// (Resubmitted unchanged after R9 infra failure: "container failed twice".)
// ---------------------------------------------------------------------------
__global__ __launch_bounds__(256, 2) void gat_k3_attn(
    const int* __restrict__ adj, const float* __restrict__ f1L,
    const float* __restrict__ f2L, const unsigned* __restrict__ f2mxEnc,
    const _Float16* __restrict__ whT2,
    _Float16* __restrict__ Ph,     // 8 slabs x 8192x256 fp16, permuted
    float* __restrict__ L)         // [8][8192]
{
    __shared__ __align__(16) _Float16 sB[2][16384];   // 2 x 32 KB (full 64-key tile)

    const int bx = blockIdx.x;
    const int q  = bx & 7;           // key slice 0..7
    const int rb = bx >> 3;          // row group 0..63
    const int wv = threadIdx.x >> 6;
    const int lane = threadIdx.x & 63;
    const int l15 = lane & 15;
    const int quad = lane >> 4;

    const int kq = q * 1024;
    const int r0 = rb * 128 + wv * 32;
    const int rA = r0 + l15;
    const int rB = rA + 16;

    const float fmxL = dec_f32(*f2mxEnc);
    const float f1A = f1L[rA];
    const float f1B = f1L[rB];
    const float sA = f1A + fmxL;
    const float sBv = f1B + fmxL;
    const float CA = fmaxf(sA, GAT_ALPHA * sA);
    const float CB = fmaxf(sBv, GAT_ALPHA * sBv);
    // exp2 arg = max(xa, a*xa) - C = max((f1-C)+f2j, (a*f1-C)+a*f2j)
    const float uA = f1A - CA, vA = GAT_ALPHA * f1A - CA;
    const float uB = f1B - CB, vB = GAT_ALPHA * f1B - CB;

    f32x4 acc[2][16];
    #pragma unroll
    for (int s = 0; s < 2; ++s)
        #pragma unroll
        for (int t = 0; t < 16; ++t) {
            f32x4 z = {0.f,0.f,0.f,0.f};
            acc[s][t] = z;
        }
    float d0 = 0.f, d1 = 0.f;

    // Raw adj tile pointers. Keys for (step,k2,j): step*64 + k2*32 + quad*8 + j.
    const int* aprA = adj + (size_t)rA * GAT_N + kq + quad * 8;
    const int* aprB = adj + (size_t)rB * GAT_N + kq + quad * 8;
    const float* f2q = f2L + kq + quad * 8;

    // 8 named iv4 regs (static indexing; runtime-indexed arrays spill).
    // NONTEMPORAL: one-shot stream, keep it out of L2 (protect whT2).
    iv4 xA0, xA1, xA2, xA3, xB0, xB1, xB2, xB3;
    #define ADJLOAD(s)                                                         \
        {                                                                      \
            const iv4* pa = reinterpret_cast<const iv4*>(aprA + (s) * 64);     \
            const iv4* pb = reinterpret_cast<const iv4*>(aprB + (s) * 64);     \
            xA0 = __builtin_nontemporal_load(pa);                              \
            xA1 = __builtin_nontemporal_load(pa + 1);                          \
            xA2 = __builtin_nontemporal_load(pa + 8);                          \
            xA3 = __builtin_nontemporal_load(pa + 9);                          \
            xB0 = __builtin_nontemporal_load(pb);                              \
            xB1 = __builtin_nontemporal_load(pb + 1);                          \
            xB2 = __builtin_nontemporal_load(pb + 8);                          \
            xB3 = __builtin_nontemporal_load(pb + 9);                          \
        }
    // bit (k2*8 + j) of mask <-> key step*64 + k2*32 + quad*8 + j
    #define ADJPACK(ma, mb)                                                    \
        {                                                                      \
            ma = pack8(xA0, xA1) | (pack8(xA2, xA3) << 8);                     \
            mb = pack8(xB0, xB1) | (pack8(xB2, xB3) << 8);                     \
        }

    // STAGE(buf, step): copy full 64-key tile (32 KB) from whT2. Pure linear
    // copy: wave wv covers halves [wv*4096, wv*4096+4096); instr i copies
    // 1 KB (64 lanes x 16 B, unit-stride). PER-LANE global addr = base +
    // lane*8 halves; LDS dest implicit lane*16.
    const _Float16* tile0 = whT2 + (size_t)(q * 16) * 16384 + (size_t)lane * 8;
    #define STAGE(buf, step)                                                   \
        {                                                                      \
            _Pragma("unroll")                                                  \
            for (int i = 0; i < 8; ++i) {                                      \
                const int off = wv * 4096 + i * 512;                           \
                const _Float16* gp = tile0 + (size_t)(step) * 16384 + off;     \
                _Float16* lp = &sB[buf][off];                                  \
                __builtin_amdgcn_global_load_lds(                              \
                    (const __attribute__((address_space(1))) void*)gp,         \
                    (__attribute__((address_space(3))) void*)lp, 16, 0, 0);    \
            }                                                                  \
        }

    ADJLOAD(0)
    float4 nfa = *reinterpret_cast<const float4*>(f2q);
    float4 nfb = *reinterpret_cast<const float4*>(f2q + 4);
    STAGE(0, 0)
    unsigned cmA, cmB;
    ADJPACK(cmA, cmB)                // waits step-0 adj loads (prologue only)
    unsigned nmA = 0, nmB = 0;
    __syncthreads();   // buf0 staged (barrier drains vmcnt)

    for (int step = 0; step < 16; ++step) {   // 64 keys per step
        const int cur = step & 1;
        if (step < 15) {
            ADJLOAD(step + 1)                 // issue early, pack at step end
            STAGE(1 - cur, step + 1)
        }

        #pragma unroll
        for (int k2 = 0; k2 < 2; ++k2) {    // sub = 32 keys (one MFMA K)
            const int u = step * 2 + k2;
            const float4 cfa = nfa, cfb = nfb;
            if (u < 31) {
                nfa = *reinterpret_cast<const float4*>(f2q + (u + 1) * 32);
                nfb = *reinterpret_cast<const float4*>(f2q + (u + 1) * 32 + 4);
            }
            const unsigned mA = (cmA >> (k2 * 8)) & 0xffu;
            const unsigned mB = (cmB >> (k2 * 8)) & 0xffu;
            const float f2v[8] = {cfa.x, cfa.y, cfa.z, cfa.w,
                                  cfb.x, cfb.y, cfb.z, cfb.w};
            float af2[8];
            #pragma unroll
            for (int j = 0; j < 8; ++j) af2[j] = GAT_ALPHA * f2v[j];

            half8 pA, pB;
            #pragma unroll
            for (int j = 0; j < 8; ++j) {
                float pa = __builtin_amdgcn_exp2f(fmaxf(uA + f2v[j], vA + af2[j]));
                pa = (mA & (1u << j)) ? pa : 0.f;
                d0 += pa;
                pA[j] = (_Float16)pa;
                float pb = __builtin_amdgcn_exp2f(fmaxf(uB + f2v[j], vB + af2[j]));
                pb = (mB & (1u << j)) ? pb : 0.f;
                d1 += pb;
                pB[j] = (_Float16)pb;
            }

            // chunk koct = k2*4+quad; halves = koct*2048 + feat*8 + key7
            const int lbase = (k2 * 4 + quad) * 2048 + l15 * 8;
            #pragma unroll
            for (int t = 0; t < 16; ++t) {
                half8 bf = *reinterpret_cast<const half8*>(
                    &sB[cur][lbase + t * 128]);
                acc[0][t] = __builtin_amdgcn_mfma_f32_16x16x32_f16(pA, bf, acc[0][t], 0, 0, 0);
                acc[1][t] = __builtin_amdgcn_mfma_f32_16x16x32_f16(pB, bf, acc[1][t], 0, 0, 0);
            }
        }
        if (step < 15) ADJPACK(nmA, nmB)      // loads landed under this step
        __syncthreads();   // drains stage(step+1) + this step's ds_reads
        cmA = nmA; cmB = nmB;
    }
    #undef STAGE
    #undef ADJLOAD
    #undef ADJPACK

    // Row denominators (one block per (rb,q) -> write unconditionally).
    d0 += __shfl_xor(d0, 16); d0 += __shfl_xor(d0, 32);
    d1 += __shfl_xor(d1, 16); d1 += __shfl_xor(d1, 32);
    if (lane < 16) {
        float* Lq = L + q * GAT_N;
        Lq[rA] = d0; Lq[rB] = d1;
    }

    // Coalesced permuted fp16 partial store; NONTEMPORAL (write-once stream,
    // read once by K4 -> keep out of L2).
    const int wid = rb * 4 + wv;                       // 0..255
    _Float16* Pq = Ph + ((size_t)q * 256 + wid) * 8192;
    #pragma unroll
    for (int s = 0; s < 2; ++s)
        #pragma unroll
        for (int t = 0; t < 16; ++t) {
            half4 hv;
            #pragma unroll
            for (int r = 0; r < 4; ++r) hv[r] = (_Float16)acc[s][t][r];
            __builtin_nontemporal_store(hv,
                reinterpret_cast<half4*>(Pq + (size_t)(((s * 16 + t) * 64 + lane) * 4)));
        }
}

// ---------------------------------------------------------------------------
// K4: un-permute + combine 8 fp16 partials, normalize, ELU, write out.
// ---------------------------------------------------------------------------
__global__ __launch_bounds__(256) void gat_k4_final(
    const _Float16* __restrict__ Ph, const float* __restrict__ L,
    float* __restrict__ out)
{
    const int tid = threadIdx.x;
    const int wid = blockIdx.x >> 3;                   // wave-chunk 0..255
    __shared__ float s_rl[32];
    if (tid < 32) {
        const int row = wid * 32 + tid;
        float s = 0.f;
        #pragma unroll
        for (int q = 0; q < GAT_NQ; ++q) s += L[q * GAT_N + row];
        s_rl[tid] = 1.0f / fmaxf(s, 1e-30f);
    }
    __syncthreads();

    const int idx = blockIdx.x * 256 + tid;            // half4 position
    const int rem = idx & 2047;                        // within wave-chunk
    const int lane = rem & 63;
    const int st = rem >> 6;
    const int s = st >> 4, t = st & 15;
    const int l15 = lane & 15, quad = lane >> 4;
    const int lrow0 = s * 16 + quad * 4;               // local rows lrow0..+3
    const int col = t * 16 + l15;

    float accv[4] = {0.f, 0.f, 0.f, 0.f};
    #pragma unroll
    for (int q = 0; q < GAT_NQ; ++q) {
        half4 v = *reinterpret_cast<const half4*>(
            Ph + ((size_t)q * 256 + wid) * 8192 + (size_t)rem * 4);
        #pragma unroll
        for (int r = 0; r < 4; ++r) accv[r] += (float)v[r];
    }
    #pragma unroll
    for (int r = 0; r < 4; ++r) {
        const float v = accv[r] * s_rl[lrow0 + r];
        const float o = v > 0.f ? v : expm1f(v);
        out[(size_t)(wid * 32 + lrow0 + r) * GAT_F + col] = o;
    }
}

// ---------------------------------------------------------------------------
extern "C" void kernel_launch(void* const* d_in, const int* in_sizes, int n_in,
                              void* d_out, int out_size, void* d_ws, size_t ws_size,
                              hipStream_t stream)
{
    const float* h   = (const float*)d_in[0];
    const int*   adj = (const int*)d_in[1];
    // d_in[2] = cv_values: constant per softmax row -> cancels exactly; unused.
    const float* W   = (const float*)d_in[3];
    const float* a   = (const float*)d_in[4];
    float* out = (float*)d_out;
    char* ws = (char*)d_ws;

    const size_t SLAB = (size_t)GAT_N * GAT_F * 2;     // 4 MiB (fp16 matrix)

    size_t off = 0;
    _Float16* whT2 = (_Float16*)(ws + off); off += SLAB;           // 4 MiB tiled
    _Float16* Ph  = (_Float16*)(ws + off); off += GAT_NQ * SLAB;   // 32 MiB
    _Float16* WT  = (_Float16*)(ws + off); off += (size_t)GAT_F * GAT_F * 2;  // 128 KiB
    float* f1L = (float*)(ws + off); off += GAT_N * 4;
    float* f2L = (float*)(ws + off); off += GAT_N * 4;
    float* L   = (float*)(ws + off); off += GAT_NQ * GAT_N * 4;
    unsigned* f2mxEnc = (unsigned*)(ws + off); off += 256;

    gat_k0b_convert<<<256, 256, 0, stream>>>(W, WT, f2mxEnc);
    gat_k1_gemm<<<512, 256, 0, stream>>>(h, WT, a, whT2, f1L, f2L, f2mxEnc);
    gat_k3_attn<<<512, 256, 0, stream>>>(adj, f1L, f2L, f2mxEnc, whT2, Ph, L);
    gat_k4_final<<<2048, 256, 0, stream>>>(Ph, L, out);
}